// Round 6
// baseline (179.201 us; speedup 1.0000x reference)
//
#include <hip/hip_runtime.h>
#include <hip/hip_bf16.h>
#include <stdint.h>

typedef __attribute__((ext_vector_type(8))) short short8;
typedef __attribute__((ext_vector_type(4))) float floatx4;
typedef __attribute__((ext_vector_type(4))) unsigned int uintx4;
typedef __attribute__((ext_vector_type(2))) unsigned int uintx2;
typedef unsigned int u32;

#define HH 64
#define WW 64
#define HWSZ 4096
#define BB 8
#define CIN 256
#define COUT 256
#define NTOT 32768  // B*H*W

__device__ __forceinline__ unsigned short f2b(float f) {
    union { float f; unsigned int u; } v; v.f = f;
    unsigned int r = v.u + 0x7FFFu + ((v.u >> 16) & 1u);
    return (unsigned short)(r >> 16);
}
__device__ __forceinline__ float b2f(unsigned short h) {
    union { unsigned int u; float f; } v; v.u = ((unsigned int)h) << 16;
    return v.f;
}
// hw packed f32->bf16 (RNE, same result as f2b for finite inputs)
__device__ __forceinline__ unsigned int pk2(float lo, float hi) {
    unsigned int r;
    asm("v_cvt_pk_bf16_f32 %0, %1, %2" : "=v"(r) : "v"(lo), "v"(hi));
    return r;
}

// ---- weight cast ---- (unchanged)
__global__ void wcast(const float* __restrict__ wq, const float* __restrict__ wk,
                      const float* __restrict__ wv,
                      unsigned short* __restrict__ wqb, unsigned short* __restrict__ wkb,
                      unsigned short* __restrict__ wvb) {
    int idx = blockIdx.x * 256 + threadIdx.x;
    wqb[idx] = f2b(wq[idx]);
    wkb[idx] = f2b(wk[idx]);
    wvb[idx] = f2b(wv[idx]);
}

// ---- GEMM v10: resident-B, stage-once, zero main-loop barriers ----
// Block = one z (Q/K/V) x one 128-px n-tile. Stages the FULL K=256 B panel
// (f32 -> cvt_pk -> bf16 LDS, 64 KB, 5-bit XOR granule swizzle) in ONE phase
// with ONE __syncthreads. A (weights) is read as 16-B register fragments
// straight from global (L2-broadcast, no LDS, no barriers). Both m0 halves
// computed from the resident B panel. Per-output k order = chunks 0..7 as
// before -> bitwise-identical results.
// LDS layout: row s (0..127) holds n = 4*(s&31)+(s>>5); 16B granule gk
// (k elems gk*8..+7) stored at byte s*512 + ((gk ^ (s&31))<<4).
__global__ __launch_bounds__(256)
void gemm_qkv(const unsigned short* __restrict__ wqb, const unsigned short* __restrict__ wkb,
              const unsigned short* __restrict__ wvb,
              const float* __restrict__ xf, const float* __restrict__ yf,
              unsigned short* __restrict__ Qb, unsigned short* __restrict__ Kb,
              unsigned short* __restrict__ Vb) {
    __shared__ unsigned char lB[65536];   // 128 rows x 256 k bf16, swizzled

    // ---- XCD-aware decode: 768 = 8 XCD x (32 n-groups x 3 z) ----
    int d = blockIdx.x;
    int X = d & 7;
    int kk = d >> 3;          // 0..95
    int g = kk / 3;           // n-group 0..31 on this XCD
    int z = kk - g * 3;       // 0..2 (z-siblings adjacent -> share x tile in L2)
    int n_tile = g * 8 + X;   // 0..255
    int n0 = n_tile * 128;

    const unsigned short* Wb = (z == 0) ? wqb : (z == 1) ? wkb : wvb;
    const float* In = (z == 0) ? yf : xf;
    unsigned short* Out = (z == 0) ? Qb : (z == 1) ? Kb : Vb;

    int bb = n0 >> 12;        // batch
    int p0 = n0 & 4095;       // pixel offset within batch
    int t = threadIdx.x;
    int lane = t & 63;
    int wave = t >> 6;
    int quad = lane >> 4;
    int l16 = lane & 15;
    int wm = (wave >> 1) * 64;
    int wn = (wave & 1) * 64;

    // ---- B stage: thread owns 4 n (rows j*32+(t&31)) x 4 k per 32-chunk ----
    int sb = t & 31;
    int kq0 = (t >> 5) * 4;            // 0,4,...,28
    int kq0h = kq0 >> 3;               // granule index within chunk pair
    int kq0b = (kq0 & 4) * 2;          // byte offset within 16B granule (0|8)
    const float* gB = In + ((size_t)bb * CIN + kq0) * HWSZ + p0 + 4 * sb;
    int sxor[4], sboff[4];
    #pragma unroll
    for (int jj = 0; jj < 4; ++jj) {
        int s = jj * 32 + sb;
        sxor[jj] = s & 31;
        sboff[jj] = s * 512 + kq0b;
    }

    #pragma unroll
    for (int c = 0; c < 8; ++c) {
        floatx4 v[4];
        #pragma unroll
        for (int i = 0; i < 4; ++i)
            v[i] = *(const floatx4*)(gB + (size_t)(c * 32 + i) * HWSZ);
        int gk = c * 4 + kq0h;
        #pragma unroll
        for (int jj = 0; jj < 4; ++jj) {
            unsigned int d0 = pk2(v[0][jj], v[1][jj]);
            unsigned int d1 = pk2(v[2][jj], v[3][jj]);
            *(uintx2*)(lB + sboff[jj] + ((gk ^ sxor[jj]) << 4)) = (uintx2){d0, d1};
        }
    }
    __syncthreads();   // the ONLY barrier in this kernel

    // ---- compute: two m0 passes over the resident B panel ----
    int rBr = (wn >> 2) + l16;
    #pragma unroll
    for (int mp = 0; mp < 2; ++mp) {
        int m0 = mp * 128;
        floatx4 acc[4][4];
        #pragma unroll
        for (int mi = 0; mi < 4; ++mi)
            #pragma unroll
            for (int ni = 0; ni < 4; ++ni)
                acc[mi][ni] = (floatx4){0.f, 0.f, 0.f, 0.f};

        #pragma unroll
        for (int c = 0; c < 8; ++c) {
            short8 af[4], bf[4];
            #pragma unroll
            for (int mi = 0; mi < 4; ++mi)
                af[mi] = *(const short8*)(Wb + (size_t)(m0 + wm + mi * 16 + l16) * CIN
                                          + c * 32 + quad * 8);
            #pragma unroll
            for (int ni = 0; ni < 4; ++ni) {
                int r = rBr + ni * 32;
                bf[ni] = *(const short8*)(lB + r * 512 + (((c * 4 + quad) ^ (r & 31)) << 4));
            }
            #pragma unroll
            for (int mi = 0; mi < 4; ++mi)
                #pragma unroll
                for (int ni = 0; ni < 4; ++ni)
                    acc[mi][ni] = __builtin_amdgcn_mfma_f32_16x16x32_bf16(af[mi], bf[ni], acc[mi][ni], 0, 0, 0);
        }

        // epilogue: lane owns cols n0+wn+4*l16 .. +3, rows m0+wm+mi*16+quad*4+r
        int colb = n0 + wn + 4 * l16;
        #pragma unroll
        for (int mi = 0; mi < 4; ++mi) {
            #pragma unroll
            for (int r = 0; r < 4; ++r) {
                int row = m0 + wm + mi * 16 + quad * 4 + r;
                unsigned int lo = (unsigned int)f2b(acc[mi][0][r]) | ((unsigned int)f2b(acc[mi][1][r]) << 16);
                unsigned int hi = (unsigned int)f2b(acc[mi][2][r]) | ((unsigned int)f2b(acc[mi][3][r]) << 16);
                *(uintx2*)(Out + (size_t)row * NTOT + colb) = (uintx2){lo, hi};
            }
        }
    }
}

// ---- attention v4: 8 outputs/thread, BRANCH-FREE clamped loads + cndmask ----
// (unchanged)
__global__ __launch_bounds__(256)
void attn(const unsigned short* __restrict__ Q,
          const unsigned short* __restrict__ K,
          const unsigned short* __restrict__ V,
          const float* __restrict__ rel_h,
          const float* __restrict__ rel_w,
          float* __restrict__ out) {
    int gid = blockIdx.x * 256 + threadIdx.x;
    int w8 = gid & 7;
    int w0 = w8 << 3;
    int h = (gid >> 3) & 63;
    int c = (gid >> 9) & 255;
    int b = gid >> 17;

    size_t nb = (size_t)c * NTOT + (size_t)b * HWSZ;
    const unsigned short* Kp = K + nb;
    const unsigned short* Vp = V + nb;

    short8 qr = *(const short8*)(Q + nb + h * 64 + w0);

    bool use_h = (c < 128);
    float rel3[3];
    if (use_h) {
        rel3[0] = rel_h[c * 3 + 0]; rel3[1] = rel_h[c * 3 + 1]; rel3[2] = rel_h[c * 3 + 2];
    } else {
        int cc = c - 128;
        rel3[0] = rel_w[cc * 3 + 0]; rel3[1] = rel_w[cc * 3 + 1]; rel3[2] = rel_w[cc * 3 + 2];
    }
    float rr[9];
    #pragma unroll
    for (int r = 0; r < 3; ++r)
        #pragma unroll
        for (int j = 0; j < 3; ++j)
            rr[r * 3 + j] = use_h ? rel3[r] : rel3[j];

    int e0 = (w0 > 0) ? w0 - 1 : 0;      // always in-row
    int e9 = (w0 < 56) ? w0 + 8 : 63;
    bool okL = (w0 > 0);
    bool okR = (w0 < 56);

    float kb[3][10], vb[3][10];
    #pragma unroll
    for (int r = 0; r < 3; ++r) {
        int ihr = h + r - 1;
        bool rok = (unsigned)ihr < 64u;
        int ihc = ihr < 0 ? 0 : (ihr > 63 ? 63 : ihr);
        int ro = ihc * 64;
        short8 km = *(const short8*)(Kp + ro + w0);
        short8 vm = *(const short8*)(Vp + ro + w0);
        float ke0 = b2f(Kp[ro + e0]), ve0 = b2f(Vp[ro + e0]);
        float ke9 = b2f(Kp[ro + e9]), ve9 = b2f(Vp[ro + e9]);
        #pragma unroll
        for (int i = 0; i < 8; ++i) {
            kb[r][i + 1] = rok ? b2f((unsigned short)km[i]) : 0.f;
            vb[r][i + 1] = rok ? b2f((unsigned short)vm[i]) : 0.f;
        }
        bool ok0 = rok && okL;
        bool ok9 = rok && okR;
        kb[r][0] = ok0 ? ke0 : 0.f;  vb[r][0] = ok0 ? ve0 : 0.f;
        kb[r][9] = ok9 ? ke9 : 0.f;  vb[r][9] = ok9 ? ve9 : 0.f;
    }

    float q[8];
    #pragma unroll
    for (int i = 0; i < 8; ++i) q[i] = b2f((unsigned short)qr[i]);

    float ov[8];
    #pragma unroll
    for (int wi = 0; wi < 8; ++wi) {
        float qv = q[wi];
        float lg[9];
        #pragma unroll
        for (int r = 0; r < 3; ++r)
            #pragma unroll
            for (int j = 0; j < 3; ++j)
                lg[r * 3 + j] = qv * (kb[r][wi + j] + rr[r * 3 + j]);
        float m = lg[0];
        #pragma unroll
        for (int t2 = 1; t2 < 9; ++t2) m = fmaxf(m, lg[t2]);
        float s = 0.f, o = 0.f;
        #pragma unroll
        for (int r = 0; r < 3; ++r)
            #pragma unroll
            for (int j = 0; j < 3; ++j) {
                float e = __expf(lg[r * 3 + j] - m);
                s += e;
                o += e * vb[r][wi + j];
            }
        ov[wi] = o * __builtin_amdgcn_rcpf(s);
    }

    size_t oi = ((size_t)b * COUT + c) * HWSZ + h * 64 + w0;
    *(floatx4*)(out + oi)     = (floatx4){ ov[0], ov[1], ov[2], ov[3] };
    *(floatx4*)(out + oi + 4) = (floatx4){ ov[4], ov[5], ov[6], ov[7] };
}

extern "C" void kernel_launch(void* const* d_in, const int* in_sizes, int n_in,
                              void* d_out, int out_size, void* d_ws, size_t ws_size,
                              hipStream_t stream) {
    const float* x = (const float*)d_in[0];
    const float* y = (const float*)d_in[1];
    const float* wq = (const float*)d_in[2];
    const float* wk = (const float*)d_in[3];
    const float* wv = (const float*)d_in[4];
    const float* rel_h = (const float*)d_in[5];
    const float* rel_w = (const float*)d_in[6];
    float* out = (float*)d_out;

    char* ws = (char*)d_ws;
    unsigned short* wqb = (unsigned short*)(ws + 33554432);
    unsigned short* wkb = (unsigned short*)(ws + 33554432 + 131072);
    unsigned short* wvb = (unsigned short*)(ws + 33554432 + 262144);
    unsigned short* Qb  = (unsigned short*)(ws + 33947648);
    unsigned short* Kb  = (unsigned short*)(ws + 33947648 + 16777216);
    unsigned short* Vb  = (unsigned short*)(ws + 33947648 + 33554432);

    wcast<<<256, 256, 0, stream>>>(wq, wk, wv, wqb, wkb, wvb);
    gemm_qkv<<<768, 256, 0, stream>>>(wqb, wkb, wvb, x, y, Qb, Kb, Vb);
    attn<<<4096, 256, 0, stream>>>(Qb, Kb, Vb, rel_h, rel_w, out);
}